// Round 2
// baseline (243.200 us; speedup 1.0000x reference)
//
#include <hip/hip_runtime.h>
#include <hip/hip_bf16.h>

// GRU cell v2: barrier-free K-loops, B-in-registers (weights L2-resident),
// padded LDS x/h tiles (row stride 264 shorts) for conflict-free A-frag reads.
// 512 blocks x 512 threads; wave grid 1x8; wave tile 128 rows x 32 cols.
// Passes: r -> z -> h (x-chunk | rh-chunk), rh passed through regs + x_l overwrite.

typedef __attribute__((ext_vector_type(8))) short s8v;           // 8 bf16 = 4 VGPR
typedef __attribute__((ext_vector_type(8))) unsigned short us8;
typedef __attribute__((ext_vector_type(4))) float f32x4;
typedef __attribute__((ext_vector_type(4))) float f4v;

#define LDW 264   // LDS row stride in shorts: 256 + 8 pad -> 528 B, breaks bank alias

__device__ __forceinline__ float bf2f(unsigned short u) {
  union { unsigned int i; float f; } c; c.i = ((unsigned int)u) << 16; return c.f;
}
__device__ __forceinline__ unsigned short f2bf(float f) {
  union { float f; unsigned int i; } c; c.f = f;
  return (unsigned short)((c.i + 0x7fffu + ((c.i >> 16) & 1u)) >> 16);  // RNE
}
__device__ __forceinline__ unsigned int pack2(float lo, float hi) {
  return (unsigned int)f2bf(lo) | ((unsigned int)f2bf(hi) << 16);
}
__device__ __forceinline__ float sig_(float s)  { return 1.0f / (1.0f + __expf(-s)); }
__device__ __forceinline__ float tanh_(float s) { return 2.0f / (1.0f + __expf(-2.0f * s)) - 1.0f; }

// ---------------- weight prep: fp32 [K][N] -> bf16 [N][K] concatenated ----------------
__global__ void gru_prep(const float* __restrict__ Wz, const float* __restrict__ Uz,
                         const float* __restrict__ Wr, const float* __restrict__ Ur,
                         const float* __restrict__ Wh, const float* __restrict__ Uh,
                         unsigned short* __restrict__ wzr, unsigned short* __restrict__ whh) {
  int idx = blockIdx.x * 256 + threadIdx.x;
  if (idx < 512 * 512) {
    int n = idx >> 9, k = idx & 511;
    int nn = n & 255;
    float v;
    if (n < 256) v = (k < 256) ? Wz[k * 256 + nn] : Uz[(k - 256) * 256 + nn];
    else         v = (k < 256) ? Wr[k * 256 + nn] : Ur[(k - 256) * 256 + nn];
    wzr[idx] = f2bf(v);
  } else if (idx < 512 * 512 + 256 * 512) {
    int j = idx - 512 * 512;
    int n = j >> 9, k = j & 511;
    float v = (k < 256) ? Wh[k * 256 + n] : Uh[(k - 256) * 256 + n];
    whh[j] = f2bf(v);
  }
}

// ---- one K=256 chunk: B fragments from global (L2-hot), A from LDS; NO barriers ----
__device__ __forceinline__ void gemm256(f32x4 acc[8][2],
    const unsigned short* __restrict__ Bsrc, int koff,
    const unsigned short* A_lds, int cb, int l15, int lg4) {
  s8v bq[2][8];
#pragma unroll
  for (int fb = 0; fb < 2; ++fb) {
    const unsigned short* bp = Bsrc + (cb + fb * 16 + l15) * 512 + koff + lg4 * 8;
#pragma unroll
    for (int kc = 0; kc < 8; ++kc)
      bq[fb][kc] = *(const s8v*)(bp + kc * 32);
  }
#pragma unroll
  for (int kc = 0; kc < 8; ++kc) {
    s8v af[8];
    const unsigned short* ap = A_lds + l15 * LDW + kc * 32 + lg4 * 8;
#pragma unroll
    for (int fa = 0; fa < 8; ++fa)
      af[fa] = *(const s8v*)(ap + fa * 16 * LDW);
#pragma unroll
    for (int fa = 0; fa < 8; ++fa)
#pragma unroll
      for (int fb = 0; fb < 2; ++fb)
        acc[fa][fb] = __builtin_amdgcn_mfma_f32_16x16x32_bf16(af[fa], bq[fb][kc], acc[fa][fb], 0, 0, 0);
  }
}

// ---------------- main fused kernel ----------------
__global__ __launch_bounds__(512, 2) void gru_main(
    const float* __restrict__ x, const float* __restrict__ hp,
    const unsigned short* __restrict__ wzr, const unsigned short* __restrict__ whh,
    const float* __restrict__ bz, const float* __restrict__ br, const float* __restrict__ bh,
    float* __restrict__ out)
{
  __shared__ __align__(16) unsigned short x_l[128 * LDW];   // 66 KB (padded)
  __shared__ __align__(16) unsigned short h_l[128 * LDW];   // 66 KB

  const int tid = threadIdx.x;
  const int lane = tid & 63;
  const int wv = tid >> 6;
  const int l15 = lane & 15, lg4 = lane >> 4;
  const int cb = wv * 32;                      // wave's 32-col slice
  const int blk = blockIdx.x;
  const int row0 = blk * 128;

  // ---- stage x, h tiles to LDS (fp32 -> bf16), one row per thread-quarter
  {
    const int srow = tid & 127;
    const int part = tid >> 7;                 // 0..3, 64 cols each
    const float* xs = x  + (size_t)(row0 + srow) * 256 + part * 64;
    const float* hs = hp + (size_t)(row0 + srow) * 256 + part * 64;
    unsigned short* xd = x_l + srow * LDW + part * 64;
    unsigned short* hd = h_l + srow * LDW + part * 64;
#pragma unroll
    for (int j = 0; j < 8; ++j) {
      f4v v0 = *(const f4v*)(xs + j * 8);
      f4v v1 = *(const f4v*)(xs + j * 8 + 4);
      us8 o;
      o[0]=f2bf(v0[0]); o[1]=f2bf(v0[1]); o[2]=f2bf(v0[2]); o[3]=f2bf(v0[3]);
      o[4]=f2bf(v1[0]); o[5]=f2bf(v1[1]); o[6]=f2bf(v1[2]); o[7]=f2bf(v1[3]);
      *(us8*)(xd + j * 8) = o;
    }
#pragma unroll
    for (int j = 0; j < 8; ++j) {
      f4v v0 = *(const f4v*)(hs + j * 8);
      f4v v1 = *(const f4v*)(hs + j * 8 + 4);
      us8 o;
      o[0]=f2bf(v0[0]); o[1]=f2bf(v0[1]); o[2]=f2bf(v0[2]); o[3]=f2bf(v0[3]);
      o[4]=f2bf(v1[0]); o[5]=f2bf(v1[1]); o[6]=f2bf(v1[2]); o[7]=f2bf(v1[3]);
      *(us8*)(hd + j * 8) = o;
    }
  }
  __syncthreads();

  f32x4 acc[8][2];
  unsigned int zp[8][2][2];    // z gate, packed bf16 (rows 2p,2p+1)
  unsigned int rhp[8][2][2];   // r*h, packed bf16
  const int colb[2] = { cb + l15, cb + 16 + l15 };

  // ===== PASS r: r = sigmoid(x Wr + h Ur + br); rh = r*h -> regs
#pragma unroll
  for (int fa = 0; fa < 8; ++fa)
#pragma unroll
    for (int fb = 0; fb < 2; ++fb) acc[fa][fb] = (f32x4){0.f,0.f,0.f,0.f};
  gemm256(acc, wzr + 256 * 512, 0,   x_l, cb, l15, lg4);
  gemm256(acc, wzr + 256 * 512, 256, h_l, cb, l15, lg4);
  {
    float bv0 = br[colb[0]], bv1 = br[colb[1]];
#pragma unroll
    for (int fa = 0; fa < 8; ++fa)
#pragma unroll
      for (int fb = 0; fb < 2; ++fb) {
        f32x4 a = acc[fa][fb];
        float bv = fb ? bv1 : bv0;
        int col = colb[fb];
#pragma unroll
        for (int p = 0; p < 2; ++p) {
          int row = fa * 16 + lg4 * 4 + 2 * p;
          float r0 = sig_(a[2 * p]     + bv);
          float r1 = sig_(a[2 * p + 1] + bv);
          float h0 = bf2f(h_l[row * LDW + col]);
          float h1 = bf2f(h_l[(row + 1) * LDW + col]);
          rhp[fa][fb][p] = pack2(r0 * h0, r1 * h1);
        }
      }
  }

  // ===== PASS z: z = sigmoid(x Wz + h Uz + bz) -> regs (packed)
#pragma unroll
  for (int fa = 0; fa < 8; ++fa)
#pragma unroll
    for (int fb = 0; fb < 2; ++fb) acc[fa][fb] = (f32x4){0.f,0.f,0.f,0.f};
  gemm256(acc, wzr, 0,   x_l, cb, l15, lg4);
  gemm256(acc, wzr, 256, h_l, cb, l15, lg4);
  {
    float bv0 = bz[colb[0]], bv1 = bz[colb[1]];
#pragma unroll
    for (int fa = 0; fa < 8; ++fa)
#pragma unroll
      for (int fb = 0; fb < 2; ++fb) {
        f32x4 a = acc[fa][fb];
        float bv = fb ? bv1 : bv0;
#pragma unroll
        for (int p = 0; p < 2; ++p)
          zp[fa][fb][p] = pack2(sig_(a[2 * p] + bv), sig_(a[2 * p + 1] + bv));
      }
  }

  // ===== PASS h: h_hat = tanh(x Wh + rh Uh + bh)
#pragma unroll
  for (int fa = 0; fa < 8; ++fa)
#pragma unroll
    for (int fb = 0; fb < 2; ++fb) acc[fa][fb] = (f32x4){0.f,0.f,0.f,0.f};
  gemm256(acc, whh, 0, x_l, cb, l15, lg4);    // x-chunk (x_l still valid)

  __syncthreads();                            // all waves done reading x_l
  // overwrite x_l with rh (each (row,col) written by exactly one thread)
#pragma unroll
  for (int fa = 0; fa < 8; ++fa)
#pragma unroll
    for (int fb = 0; fb < 2; ++fb) {
      int col = colb[fb];
#pragma unroll
      for (int p = 0; p < 2; ++p) {
        int row = fa * 16 + lg4 * 4 + 2 * p;
        unsigned int w = rhp[fa][fb][p];
        x_l[row * LDW + col]       = (unsigned short)(w & 0xffffu);
        x_l[(row + 1) * LDW + col] = (unsigned short)(w >> 16);
      }
    }
  __syncthreads();                            // rh visible to all waves

  gemm256(acc, whh, 256, x_l, cb, l15, lg4);  // rh-chunk

  // ===== epilogue: h = z*h_prev + (1-z)*h_hat
  {
    float bv0 = bh[colb[0]], bv1 = bh[colb[1]];
#pragma unroll
    for (int fa = 0; fa < 8; ++fa)
#pragma unroll
      for (int fb = 0; fb < 2; ++fb) {
        f32x4 a = acc[fa][fb];
        float bv = fb ? bv1 : bv0;
        int col = colb[fb];
#pragma unroll
        for (int i = 0; i < 4; ++i) {
          int row = fa * 16 + lg4 * 4 + i;
          float hh = tanh_(a[i] + bv);
          unsigned int zw = zp[fa][fb][i >> 1];
          float z = bf2f((unsigned short)((i & 1) ? (zw >> 16) : (zw & 0xffffu)));
          float hv = bf2f(h_l[row * LDW + col]);
          out[(size_t)(row0 + row) * 256 + col] = z * hv + (1.0f - z) * hh;
        }
      }
  }
}

extern "C" void kernel_launch(void* const* d_in, const int* in_sizes, int n_in,
                              void* d_out, int out_size, void* d_ws, size_t ws_size,
                              hipStream_t stream) {
  const float* x  = (const float*)d_in[0];
  const float* hp = (const float*)d_in[1];
  const float* Wz = (const float*)d_in[2];
  const float* Uz = (const float*)d_in[3];
  const float* bz = (const float*)d_in[4];
  const float* Wr = (const float*)d_in[5];
  const float* Ur = (const float*)d_in[6];
  const float* br = (const float*)d_in[7];
  const float* Wh = (const float*)d_in[8];
  const float* Uh = (const float*)d_in[9];
  const float* bh = (const float*)d_in[10];

  if (ws_size < (size_t)(512 * 512 + 256 * 512) * sizeof(unsigned short)) return;  // need 768 KB

  unsigned short* wzr = (unsigned short*)d_ws;
  unsigned short* whh = wzr + 512 * 512;

  gru_prep<<<1536, 256, 0, stream>>>(Wz, Uz, Wr, Ur, Wh, Uh, wzr, whh);
  gru_main<<<512, 512, 0, stream>>>(x, hp, wzr, whh, bz, br, bh, (float*)d_out);
}

// Round 3
// 193.110 us; speedup vs baseline: 1.2594x; 1.2594x over previous
//
#include <hip/hip_runtime.h>
#include <hip/hip_bf16.h>

// GRU cell v3: barrier-free K-loops, B streamed from L2 per-kc (no forced live array),
// 64-row blocks (2 blocks/CU co-resident -> staging overlaps compute),
// wave tile 64x64 (fa=4, fb=4), padded LDS rows (LDW=264) for conflict-free A reads.
// Pass order z -> r -> h minimizes gate-register lifetimes.

typedef __attribute__((ext_vector_type(8))) short s8v;           // 8 bf16 = 4 VGPR
typedef __attribute__((ext_vector_type(8))) unsigned short us8;
typedef __attribute__((ext_vector_type(4))) float f32x4;
typedef __attribute__((ext_vector_type(4))) float f4v;

#define LDW 264   // LDS row stride in shorts (528 B) — breaks power-of-2 bank alias

__device__ __forceinline__ float bf2f(unsigned short u) {
  union { unsigned int i; float f; } c; c.i = ((unsigned int)u) << 16; return c.f;
}
__device__ __forceinline__ unsigned short f2bf(float f) {
  union { float f; unsigned int i; } c; c.f = f;
  return (unsigned short)((c.i + 0x7fffu + ((c.i >> 16) & 1u)) >> 16);  // RNE
}
__device__ __forceinline__ unsigned int pack2(float lo, float hi) {
  return (unsigned int)f2bf(lo) | ((unsigned int)f2bf(hi) << 16);
}
__device__ __forceinline__ float sig_(float s)  { return 1.0f / (1.0f + __expf(-s)); }
__device__ __forceinline__ float tanh_(float s) { return 2.0f / (1.0f + __expf(-2.0f * s)) - 1.0f; }

// ---------------- weight prep: fp32 [K][N] -> bf16 [N][K] concatenated ----------------
__global__ void gru_prep(const float* __restrict__ Wz, const float* __restrict__ Uz,
                         const float* __restrict__ Wr, const float* __restrict__ Ur,
                         const float* __restrict__ Wh, const float* __restrict__ Uh,
                         unsigned short* __restrict__ wzr, unsigned short* __restrict__ whh) {
  int idx = blockIdx.x * 256 + threadIdx.x;
  if (idx < 512 * 512) {
    int n = idx >> 9, k = idx & 511;
    int nn = n & 255;
    float v;
    if (n < 256) v = (k < 256) ? Wz[k * 256 + nn] : Uz[(k - 256) * 256 + nn];
    else         v = (k < 256) ? Wr[k * 256 + nn] : Ur[(k - 256) * 256 + nn];
    wzr[idx] = f2bf(v);
  } else if (idx < 512 * 512 + 256 * 512) {
    int j = idx - 512 * 512;
    int n = j >> 9, k = j & 511;
    float v = (k < 256) ? Wh[k * 256 + n] : Uh[(k - 256) * 256 + n];
    whh[j] = f2bf(v);
  }
}

// ---- one K=256 chunk: B per-kc from global (L2-hot), A from LDS; NO barriers ----
__device__ __forceinline__ void gemm256(f32x4 acc[4][4],
    const unsigned short* __restrict__ Bsrc, int koff,
    const unsigned short* A_lds, int wv, int l15, int lg4) {
  const unsigned short* bp  = Bsrc + (wv * 64 + l15) * 512 + koff + lg4 * 8;
  const unsigned short* ap0 = A_lds + l15 * LDW + lg4 * 8;
#pragma unroll
  for (int kc = 0; kc < 8; ++kc) {
    s8v bq[4], af[4];
#pragma unroll
    for (int fb = 0; fb < 4; ++fb)
      bq[fb] = *(const s8v*)(bp + fb * (16 * 512) + kc * 32);
#pragma unroll
    for (int fa = 0; fa < 4; ++fa)
      af[fa] = *(const s8v*)(ap0 + fa * (16 * LDW) + kc * 32);
#pragma unroll
    for (int fa = 0; fa < 4; ++fa)
#pragma unroll
      for (int fb = 0; fb < 4; ++fb)
        acc[fa][fb] = __builtin_amdgcn_mfma_f32_16x16x32_bf16(af[fa], bq[fb], acc[fa][fb], 0, 0, 0);
  }
}

// ---------------- main fused kernel: 64 rows per block, 4 waves ----------------
__global__ __launch_bounds__(256, 2) void gru_main(
    const float* __restrict__ x, const float* __restrict__ hp,
    const unsigned short* __restrict__ wzr, const unsigned short* __restrict__ whh,
    const float* __restrict__ bz, const float* __restrict__ br, const float* __restrict__ bh,
    float* __restrict__ out)
{
  __shared__ __align__(16) unsigned short x_l[64 * LDW];   // 33.8 KB
  __shared__ __align__(16) unsigned short h_l[64 * LDW];   // 33.8 KB -> 2 blocks/CU

  const int tid = threadIdx.x;
  const int lane = tid & 63;
  const int wv = tid >> 6;                   // 0..3 : wave's 64-col slice
  const int l15 = lane & 15, lg4 = lane >> 4;
  const int blk = blockIdx.x;
  const int row0 = blk * 64;

  // ---- stage x, h tiles to LDS (fp32 -> bf16)
  {
    const int srow = tid >> 2;               // 0..63
    const int part = tid & 3;                // 64-col quarter
    const float* xs = x  + (size_t)(row0 + srow) * 256 + part * 64;
    const float* hs = hp + (size_t)(row0 + srow) * 256 + part * 64;
    unsigned short* xd = x_l + srow * LDW + part * 64;
    unsigned short* hd = h_l + srow * LDW + part * 64;
#pragma unroll
    for (int j = 0; j < 8; ++j) {
      f4v v0 = *(const f4v*)(xs + j * 8);
      f4v v1 = *(const f4v*)(xs + j * 8 + 4);
      us8 o;
      o[0]=f2bf(v0[0]); o[1]=f2bf(v0[1]); o[2]=f2bf(v0[2]); o[3]=f2bf(v0[3]);
      o[4]=f2bf(v1[0]); o[5]=f2bf(v1[1]); o[6]=f2bf(v1[2]); o[7]=f2bf(v1[3]);
      *(us8*)(xd + j * 8) = o;
    }
#pragma unroll
    for (int j = 0; j < 8; ++j) {
      f4v v0 = *(const f4v*)(hs + j * 8);
      f4v v1 = *(const f4v*)(hs + j * 8 + 4);
      us8 o;
      o[0]=f2bf(v0[0]); o[1]=f2bf(v0[1]); o[2]=f2bf(v0[2]); o[3]=f2bf(v0[3]);
      o[4]=f2bf(v1[0]); o[5]=f2bf(v1[1]); o[6]=f2bf(v1[2]); o[7]=f2bf(v1[3]);
      *(us8*)(hd + j * 8) = o;
    }
  }
  __syncthreads();

  f32x4 acc[4][4];
  unsigned int zp[4][4][2];    // z gate, packed bf16 (rows 2p,2p+1)
  unsigned int rhp[4][4][2];   // r*h, packed bf16

  // ===== PASS z: z = sigmoid(x Wz + h Uz + bz) -> regs (packed)
#pragma unroll
  for (int fa = 0; fa < 4; ++fa)
#pragma unroll
    for (int fb = 0; fb < 4; ++fb) acc[fa][fb] = (f32x4){0.f,0.f,0.f,0.f};
  gemm256(acc, wzr, 0,   x_l, wv, l15, lg4);
  gemm256(acc, wzr, 256, h_l, wv, l15, lg4);
#pragma unroll
  for (int fb = 0; fb < 4; ++fb) {
    float bv = bz[wv * 64 + fb * 16 + l15];
#pragma unroll
    for (int fa = 0; fa < 4; ++fa) {
      f32x4 a = acc[fa][fb];
#pragma unroll
      for (int p = 0; p < 2; ++p)
        zp[fa][fb][p] = pack2(sig_(a[2 * p] + bv), sig_(a[2 * p + 1] + bv));
    }
  }

  // ===== PASS r: r = sigmoid(x Wr + h Ur + br); rh = r*h -> regs (packed)
#pragma unroll
  for (int fa = 0; fa < 4; ++fa)
#pragma unroll
    for (int fb = 0; fb < 4; ++fb) acc[fa][fb] = (f32x4){0.f,0.f,0.f,0.f};
  gemm256(acc, wzr + 256 * 512, 0,   x_l, wv, l15, lg4);
  gemm256(acc, wzr + 256 * 512, 256, h_l, wv, l15, lg4);
#pragma unroll
  for (int fb = 0; fb < 4; ++fb) {
    float bv = br[wv * 64 + fb * 16 + l15];
    int col = wv * 64 + fb * 16 + l15;
#pragma unroll
    for (int fa = 0; fa < 4; ++fa) {
      f32x4 a = acc[fa][fb];
#pragma unroll
      for (int p = 0; p < 2; ++p) {
        int row = fa * 16 + lg4 * 4 + 2 * p;
        float r0 = sig_(a[2 * p]     + bv);
        float r1 = sig_(a[2 * p + 1] + bv);
        float h0 = bf2f(h_l[row * LDW + col]);
        float h1 = bf2f(h_l[(row + 1) * LDW + col]);
        rhp[fa][fb][p] = pack2(r0 * h0, r1 * h1);
      }
    }
  }

  // ===== PASS h: h_hat = tanh(x Wh + rh Uh + bh)
#pragma unroll
  for (int fa = 0; fa < 4; ++fa)
#pragma unroll
    for (int fb = 0; fb < 4; ++fb) acc[fa][fb] = (f32x4){0.f,0.f,0.f,0.f};
  gemm256(acc, whh, 0, x_l, wv, l15, lg4);    // x-chunk (x_l still valid)

  __syncthreads();                            // all waves done reading x_l
  // overwrite x_l with rh (each (row,col) written by exactly one thread)
#pragma unroll
  for (int fb = 0; fb < 4; ++fb) {
    int col = wv * 64 + fb * 16 + l15;
#pragma unroll
    for (int fa = 0; fa < 4; ++fa)
#pragma unroll
      for (int p = 0; p < 2; ++p) {
        int row = fa * 16 + lg4 * 4 + 2 * p;
        unsigned int w = rhp[fa][fb][p];
        x_l[row * LDW + col]       = (unsigned short)(w & 0xffffu);
        x_l[(row + 1) * LDW + col] = (unsigned short)(w >> 16);
      }
  }
  __syncthreads();                            // rh visible to all waves

  gemm256(acc, whh, 256, x_l, wv, l15, lg4);  // rh-chunk

  // ===== epilogue: h = z*h_prev + (1-z)*h_hat
#pragma unroll
  for (int fb = 0; fb < 4; ++fb) {
    float bv = bh[wv * 64 + fb * 16 + l15];
    int col = wv * 64 + fb * 16 + l15;
#pragma unroll
    for (int fa = 0; fa < 4; ++fa) {
      f32x4 a = acc[fa][fb];
#pragma unroll
      for (int i = 0; i < 4; ++i) {
        int row = fa * 16 + lg4 * 4 + i;
        float hh = tanh_(a[i] + bv);
        unsigned int zw = zp[fa][fb][i >> 1];
        float z = bf2f((unsigned short)((i & 1) ? (zw >> 16) : (zw & 0xffffu)));
        float hv = bf2f(h_l[row * LDW + col]);
        out[(size_t)(row0 + row) * 256 + col] = z * hv + (1.0f - z) * hh;
      }
    }
  }
}

extern "C" void kernel_launch(void* const* d_in, const int* in_sizes, int n_in,
                              void* d_out, int out_size, void* d_ws, size_t ws_size,
                              hipStream_t stream) {
  const float* x  = (const float*)d_in[0];
  const float* hp = (const float*)d_in[1];
  const float* Wz = (const float*)d_in[2];
  const float* Uz = (const float*)d_in[3];
  const float* bz = (const float*)d_in[4];
  const float* Wr = (const float*)d_in[5];
  const float* Ur = (const float*)d_in[6];
  const float* br = (const float*)d_in[7];
  const float* Wh = (const float*)d_in[8];
  const float* Uh = (const float*)d_in[9];
  const float* bh = (const float*)d_in[10];

  if (ws_size < (size_t)(512 * 512 + 256 * 512) * sizeof(unsigned short)) return;  // need 768 KB

  unsigned short* wzr = (unsigned short*)d_ws;
  unsigned short* whh = wzr + 512 * 512;

  gru_prep<<<1536, 256, 0, stream>>>(Wz, Uz, Wr, Ur, Wh, Uh, wzr, whh);
  gru_main<<<1024, 256, 0, stream>>>(x, hp, wzr, whh, bz, br, bh, (float*)d_out);
}

// Round 4
// 132.274 us; speedup vs baseline: 1.8386x; 1.4599x over previous
//
#include <hip/hip_runtime.h>
#include <hip/hip_bf16.h>

// GRU cell v4: 8 waves x (64x32) wave tile -> persistent regs 64 (acc32+zp16+rhp16),
// fragment-major B layout (coalesced 1KB wave loads from L2), barrier-free K-loops,
// padded LDS A tiles (LDW=264). 1024 blocks x 512 threads, 64 rows/block.

typedef __attribute__((ext_vector_type(8))) short s8v;           // 8 bf16 = 4 VGPR
typedef __attribute__((ext_vector_type(8))) unsigned short us8;
typedef __attribute__((ext_vector_type(4))) float f32x4;
typedef __attribute__((ext_vector_type(4))) float f4v;

#define LDW 264   // LDS row stride in shorts (528 B): breaks power-of-2 bank alias

__device__ __forceinline__ float bf2f(unsigned short u) {
  union { unsigned int i; float f; } c; c.i = ((unsigned int)u) << 16; return c.f;
}
__device__ __forceinline__ unsigned short f2bf(float f) {
  union { float f; unsigned int i; } c; c.f = f;
  return (unsigned short)((c.i + 0x7fffu + ((c.i >> 16) & 1u)) >> 16);  // RNE
}
__device__ __forceinline__ unsigned int pack2(float lo, float hi) {
  return (unsigned int)f2bf(lo) | ((unsigned int)f2bf(hi) << 16);
}
__device__ __forceinline__ float sig_(float s)  { return 1.0f / (1.0f + __expf(-s)); }
__device__ __forceinline__ float tanh_(float s) { return 2.0f / (1.0f + __expf(-2.0f * s)) - 1.0f; }

// ---------------- weight prep: fp32 [K][N] -> bf16 fragment-major tiles ----------------
// Tile (nt, kt) = 16 n x 32 k = 512 shorts (1 KB), laid out lane-major:
//   short index within tile = lane*8 + e, where n = nt*16 + (lane&15),
//   k = kt*32 + (lane>>4)*8 + e.  Tile order: t = nt*16 + kt.
// wzr: nt 0..31 (z: nt<16 -> Wz/Uz ; r: nt>=16 -> Wr/Ur), kt 0..15 (k<256 -> W, else U).
// whh: nt 0..15 (Wh/Uh).
__global__ void gru_prep(const float* __restrict__ Wz, const float* __restrict__ Uz,
                         const float* __restrict__ Wr, const float* __restrict__ Ur,
                         const float* __restrict__ Wh, const float* __restrict__ Uh,
                         unsigned short* __restrict__ wzr, unsigned short* __restrict__ whh) {
  int idx = blockIdx.x * 256 + threadIdx.x;
  if (idx < 512 * 512) {
    int t = idx >> 9, lane = (idx >> 3) & 63, e = idx & 7;
    int nt = t >> 4, kt = t & 15;
    int n = nt * 16 + (lane & 15);
    int k = kt * 32 + ((lane >> 4) << 3) + e;
    int nn = n & 255;
    float v;
    if (n < 256) v = (k < 256) ? Wz[k * 256 + nn] : Uz[(k - 256) * 256 + nn];
    else         v = (k < 256) ? Wr[k * 256 + nn] : Ur[(k - 256) * 256 + nn];
    wzr[idx] = f2bf(v);
  } else if (idx < 512 * 512 + 256 * 512) {
    int j = idx - 512 * 512;
    int t = j >> 9, lane = (j >> 3) & 63, e = j & 7;
    int nt = t >> 4, kt = t & 15;
    int n = nt * 16 + (lane & 15);
    int k = kt * 32 + ((lane >> 4) << 3) + e;
    float v = (k < 256) ? Wh[k * 256 + n] : Uh[(k - 256) * 256 + n];
    whh[j] = f2bf(v);
  }
}

// ---- one K=256 chunk: B tiles coalesced from L2, A from LDS; NO barriers ----
// acc[fa][fb]: fa = 4 row-frags (16 each, 64 rows), fb = 2 col-frags (32 cols/wave).
__device__ __forceinline__ void gemm256(f32x4 acc[4][2],
    const unsigned short* __restrict__ Bsrc, int ntb, int kt0,
    const unsigned short* A_lds, int l15, int lg4, int lane) {
  const unsigned short* bp  = Bsrc + (((ntb * 16) + kt0) << 9) + lane * 8;
  const unsigned short* ap0 = A_lds + l15 * LDW + lg4 * 8;
#pragma unroll
  for (int kc = 0; kc < 8; ++kc) {
    s8v bq[2], af[4];
    bq[0] = *(const s8v*)(bp + kc * 512);
    bq[1] = *(const s8v*)(bp + 8192 + kc * 512);   // next nt row of tiles (16 kt * 512)
#pragma unroll
    for (int fa = 0; fa < 4; ++fa)
      af[fa] = *(const s8v*)(ap0 + fa * (16 * LDW) + kc * 32);
#pragma unroll
    for (int fa = 0; fa < 4; ++fa)
#pragma unroll
      for (int fb = 0; fb < 2; ++fb)
        acc[fa][fb] = __builtin_amdgcn_mfma_f32_16x16x32_bf16(af[fa], bq[fb], acc[fa][fb], 0, 0, 0);
  }
}

// ---------------- main fused kernel: 64 rows per block, 8 waves ----------------
__global__ __launch_bounds__(512, 2) void gru_main(
    const float* __restrict__ x, const float* __restrict__ hp,
    const unsigned short* __restrict__ wzr, const unsigned short* __restrict__ whh,
    const float* __restrict__ bz, const float* __restrict__ br, const float* __restrict__ bh,
    float* __restrict__ out)
{
  __shared__ __align__(16) unsigned short x_l[64 * LDW];   // 33.8 KB
  __shared__ __align__(16) unsigned short h_l[64 * LDW];   // 33.8 KB

  const int tid = threadIdx.x;
  const int lane = tid & 63;
  const int wv = tid >> 6;                   // 0..7 : wave's 32-col slice
  const int l15 = lane & 15, lg4 = lane >> 4;
  const int ntb = wv * 2;                    // wave's first B tile row
  const int blk = blockIdx.x;
  const int row0 = blk * 64;

  // ---- stage x, h tiles to LDS (fp32 -> bf16); 32 cols per thread
  {
    const int srow = tid >> 3;               // 0..63
    const int part = tid & 7;                // 32-col eighth
    const float* xs = x  + (size_t)(row0 + srow) * 256 + part * 32;
    const float* hs = hp + (size_t)(row0 + srow) * 256 + part * 32;
    unsigned short* xd = x_l + srow * LDW + part * 32;
    unsigned short* hd = h_l + srow * LDW + part * 32;
#pragma unroll
    for (int j = 0; j < 4; ++j) {
      f4v v0 = *(const f4v*)(xs + j * 8);
      f4v v1 = *(const f4v*)(xs + j * 8 + 4);
      us8 o;
      o[0]=f2bf(v0[0]); o[1]=f2bf(v0[1]); o[2]=f2bf(v0[2]); o[3]=f2bf(v0[3]);
      o[4]=f2bf(v1[0]); o[5]=f2bf(v1[1]); o[6]=f2bf(v1[2]); o[7]=f2bf(v1[3]);
      *(us8*)(xd + j * 8) = o;
    }
#pragma unroll
    for (int j = 0; j < 4; ++j) {
      f4v v0 = *(const f4v*)(hs + j * 8);
      f4v v1 = *(const f4v*)(hs + j * 8 + 4);
      us8 o;
      o[0]=f2bf(v0[0]); o[1]=f2bf(v0[1]); o[2]=f2bf(v0[2]); o[3]=f2bf(v0[3]);
      o[4]=f2bf(v1[0]); o[5]=f2bf(v1[1]); o[6]=f2bf(v1[2]); o[7]=f2bf(v1[3]);
      *(us8*)(hd + j * 8) = o;
    }
  }
  __syncthreads();

  f32x4 acc[4][2];
  unsigned int zp[4][2][2];    // z gate, packed bf16 (rows 2p,2p+1)  : 16 VGPR
  unsigned int rhp[4][2][2];   // r*h, packed bf16                     : 16 VGPR

  // ===== PASS z: z = sigmoid(x Wz + h Uz + bz) -> regs (packed)
#pragma unroll
  for (int fa = 0; fa < 4; ++fa)
#pragma unroll
    for (int fb = 0; fb < 2; ++fb) acc[fa][fb] = (f32x4){0.f,0.f,0.f,0.f};
  gemm256(acc, wzr, ntb, 0, x_l, l15, lg4, lane);
  gemm256(acc, wzr, ntb, 8, h_l, l15, lg4, lane);
#pragma unroll
  for (int fb = 0; fb < 2; ++fb) {
    float bv = bz[wv * 32 + fb * 16 + l15];
#pragma unroll
    for (int fa = 0; fa < 4; ++fa) {
      f32x4 a = acc[fa][fb];
#pragma unroll
      for (int p = 0; p < 2; ++p)
        zp[fa][fb][p] = pack2(sig_(a[2 * p] + bv), sig_(a[2 * p + 1] + bv));
    }
  }

  // ===== PASS r: r = sigmoid(x Wr + h Ur + br); rh = r*h -> regs (packed)
#pragma unroll
  for (int fa = 0; fa < 4; ++fa)
#pragma unroll
    for (int fb = 0; fb < 2; ++fb) acc[fa][fb] = (f32x4){0.f,0.f,0.f,0.f};
  gemm256(acc, wzr + 131072, ntb, 0, x_l, l15, lg4, lane);   // r tiles: nt 16..31
  gemm256(acc, wzr + 131072, ntb, 8, h_l, l15, lg4, lane);
#pragma unroll
  for (int fb = 0; fb < 2; ++fb) {
    float bv = br[wv * 32 + fb * 16 + l15];
    int col = wv * 32 + fb * 16 + l15;
#pragma unroll
    for (int fa = 0; fa < 4; ++fa) {
      f32x4 a = acc[fa][fb];
#pragma unroll
      for (int p = 0; p < 2; ++p) {
        int row = fa * 16 + lg4 * 4 + 2 * p;
        float r0 = sig_(a[2 * p]     + bv);
        float r1 = sig_(a[2 * p + 1] + bv);
        float h0 = bf2f(h_l[row * LDW + col]);
        float h1 = bf2f(h_l[(row + 1) * LDW + col]);
        rhp[fa][fb][p] = pack2(r0 * h0, r1 * h1);
      }
    }
  }

  // ===== PASS h: h_hat = tanh(x Wh + rh Uh + bh)
#pragma unroll
  for (int fa = 0; fa < 4; ++fa)
#pragma unroll
    for (int fb = 0; fb < 2; ++fb) acc[fa][fb] = (f32x4){0.f,0.f,0.f,0.f};
  gemm256(acc, whh, ntb, 0, x_l, l15, lg4, lane);   // x-chunk (x_l still valid)

  __syncthreads();                            // all waves done reading x_l
  // overwrite x_l with rh (each (row,col) written by exactly one thread)
#pragma unroll
  for (int fb = 0; fb < 2; ++fb) {
    int col = wv * 32 + fb * 16 + l15;
#pragma unroll
    for (int fa = 0; fa < 4; ++fa)
#pragma unroll
      for (int p = 0; p < 2; ++p) {
        int row = fa * 16 + lg4 * 4 + 2 * p;
        unsigned int w = rhp[fa][fb][p];
        x_l[row * LDW + col]       = (unsigned short)(w & 0xffffu);
        x_l[(row + 1) * LDW + col] = (unsigned short)(w >> 16);
      }
  }
  __syncthreads();                            // rh visible to all waves

  gemm256(acc, whh, ntb, 8, x_l, l15, lg4, lane);   // rh-chunk

  // ===== epilogue: h = z*h_prev + (1-z)*h_hat
#pragma unroll
  for (int fb = 0; fb < 2; ++fb) {
    float bv = bh[wv * 32 + fb * 16 + l15];
    int col = wv * 32 + fb * 16 + l15;
#pragma unroll
    for (int fa = 0; fa < 4; ++fa) {
      f32x4 a = acc[fa][fb];
#pragma unroll
      for (int i = 0; i < 4; ++i) {
        int row = fa * 16 + lg4 * 4 + i;
        float hh = tanh_(a[i] + bv);
        unsigned int zw = zp[fa][fb][i >> 1];
        float z = bf2f((unsigned short)((i & 1) ? (zw >> 16) : (zw & 0xffffu)));
        float hv = bf2f(h_l[row * LDW + col]);
        out[(size_t)(row0 + row) * 256 + col] = z * hv + (1.0f - z) * hh;
      }
    }
  }
}

extern "C" void kernel_launch(void* const* d_in, const int* in_sizes, int n_in,
                              void* d_out, int out_size, void* d_ws, size_t ws_size,
                              hipStream_t stream) {
  const float* x  = (const float*)d_in[0];
  const float* hp = (const float*)d_in[1];
  const float* Wz = (const float*)d_in[2];
  const float* Uz = (const float*)d_in[3];
  const float* bz = (const float*)d_in[4];
  const float* Wr = (const float*)d_in[5];
  const float* Ur = (const float*)d_in[6];
  const float* br = (const float*)d_in[7];
  const float* Wh = (const float*)d_in[8];
  const float* Uh = (const float*)d_in[9];
  const float* bh = (const float*)d_in[10];

  if (ws_size < (size_t)(512 * 512 + 256 * 512) * sizeof(unsigned short)) return;  // need 768 KB

  unsigned short* wzr = (unsigned short*)d_ws;
  unsigned short* whh = wzr + 512 * 512;

  gru_prep<<<1536, 256, 0, stream>>>(Wz, Uz, Wr, Ur, Wh, Uh, wzr, whh);
  gru_main<<<1024, 512, 0, stream>>>(x, hp, wzr, whh, bz, br, bh, (float*)d_out);
}